// Round 3
// baseline (12879.755 us; speedup 1.0000x reference)
//
#include <hip/hip_runtime.h>
#include <math.h>
#include <stdint.h>

// Problem constants
#define Bb 32
#define Ss 512
#define Dd 1024
#define Hh 16
#define HDd 64
#define Ll 6
#define DFFd 4096
#define Pp 64
#define BS (Bb * Ss)   // 16384 token rows

typedef _Float16 f16;
typedef _Float16 f16x8 __attribute__((ext_vector_type(8)));
typedef float f32x4 __attribute__((ext_vector_type(4)));

typedef __attribute__((address_space(3))) uint8_t  lds_b;
typedef __attribute__((address_space(1))) const uint8_t gbl_b;

// ---------------------------------------------------------------------------
// NT GEMM: C[M,N] = act( scale * A[M,K] @ Bt[N,K]^T + bias + pvec ) (* mul)
// A, Bt fp16 row-major (Bt rows are K-contiguous). 128x128 tile, 4 waves,
// each wave 4x4 MFMA 16x16x32 tiles. global_load_lds (16B) staging into
// k-segment-major LDS [seg][row][8] (m97 structure: thread t stages byte
// t*16; fragment = one ds_read_b128). Batched via blockIdx.z (z1=z/nz2).
// Out-of-range rows are address-clamped (valid duplicated data; only feeds
// discarded tiles since all K are multiples of 32 and M mult of 128 here).
// ---------------------------------------------------------------------------
template <bool BIAS, bool PVEC, bool MULV, bool RELU>
__global__ __launch_bounds__(256) void gemm_nt(
    const f16* __restrict__ A, const f16* __restrict__ Bt, f16* __restrict__ C,
    int M, int N, int K, int lda, int ldb, int ldc,
    long sA1, long sA2, long sB1, long sB2, long sC1, long sC2, int nz2,
    const float* __restrict__ bias, const float* __restrict__ pvec, int pvs,
    const float* __restrict__ mul, long sM1, long sM2, float scale)
{
    __shared__ f16 As[4 * 128 * 8];   // [seg][row][8] seg = k/8 within 32-k step
    __shared__ f16 Bs[4 * 128 * 8];

    int z = blockIdx.z;
    int z1 = z / nz2, z2 = z % nz2;
    A  += z1 * sA1 + z2 * sA2;
    Bt += z1 * sB1 + z2 * sB2;
    long coff = z1 * sC1 + z2 * sC2;
    if (MULV) mul += z1 * sM1 + z2 * sM2;

    int m0 = blockIdx.x * 128, n0 = blockIdx.y * 128;
    int t = threadIdx.x;
    int lane = t & 63, w = t >> 6;
    int wm = (w >> 1) * 64, wn = (w & 1) * 64;
    int fr = lane & 15;            // A row / B col within 16-tile
    int fs = lane >> 4;            // k-segment (8 halves each)

    // staging coords: thread t covers row (t&127), k-seg (t>>7) + 2*pass
    int srow = t & 127, sseg = t >> 7;
    int gmS = m0 + srow; if (gmS >= M) gmS = M - 1;   // clamp
    int gnS = n0 + srow; if (gnS >= N) gnS = N - 1;
    const f16* aRow = A + (long)gmS * lda + sseg * 8;
    const f16* bRow = Bt + (long)gnS * ldb + sseg * 8;
    // wave-uniform LDS byte bases: pass p, wave w -> p*4096 + w*1024
    lds_b* aDst0 = (lds_b*)As + w * 1024;
    lds_b* bDst0 = (lds_b*)Bs + w * 1024;

    f32x4 acc[4][4] = {};

    for (int k0 = 0; k0 < K; k0 += 32) {
        __syncthreads();
        #pragma unroll
        for (int p = 0; p < 2; ++p) {
            __builtin_amdgcn_global_load_lds((gbl_b*)(aRow + k0 + p * 16), aDst0 + p * 4096, 16, 0, 0);
            __builtin_amdgcn_global_load_lds((gbl_b*)(bRow + k0 + p * 16), bDst0 + p * 4096, 16, 0, 0);
        }
        __syncthreads();
        f16x8 af[4], bf[4];
        #pragma unroll
        for (int i = 0; i < 4; ++i) af[i] = *(const f16x8*)&As[(fs * 128 + wm + i * 16 + fr) * 8];
        #pragma unroll
        for (int j = 0; j < 4; ++j) bf[j] = *(const f16x8*)&Bs[(fs * 128 + wn + j * 16 + fr) * 8];
        #pragma unroll
        for (int i = 0; i < 4; ++i)
            #pragma unroll
            for (int j = 0; j < 4; ++j)
                acc[i][j] = __builtin_amdgcn_mfma_f32_16x16x32_f16(af[i], bf[j], acc[i][j], 0, 0, 0);
    }

    // epilogue: C/D layout col=lane&15, row=(lane>>4)*4+reg  [verified m89/m91]
    int cr = (lane >> 4) * 4;
    int cc = lane & 15;
    #pragma unroll
    for (int i = 0; i < 4; ++i) {
        #pragma unroll
        for (int j = 0; j < 4; ++j) {
            int gn = n0 + wn + j * 16 + cc;
            if (gn >= N) continue;
            float bvv = BIAS ? bias[gn] : 0.f;
            float mvv = MULV ? mul[gn] : 1.f;
            #pragma unroll
            for (int r = 0; r < 4; ++r) {
                int gm = m0 + wm + i * 16 + cr + r;
                if (gm >= M) continue;
                float v = acc[i][j][r] * scale + bvv;
                if (PVEC) v += pvec[(long)(gm >> pvs) * N + gn];
                if (MULV) v *= mvv;
                if (RELU) v = fmaxf(v, 0.f);
                C[coff + (long)gm * ldc + gn] = (f16)v;
            }
        }
    }
}

// fp32 [K,N] -> fp16 [N,K] transpose (weights), K,N multiples of 32
__global__ __launch_bounds__(256) void transpose_w(
    const float* __restrict__ W, f16* __restrict__ Wt, int K, int N)
{
    __shared__ float tile[32][33];
    int k0 = blockIdx.x * 32, n0 = blockIdx.y * 32;
    int tx = threadIdx.x & 31, ty = threadIdx.x >> 5;
    #pragma unroll
    for (int i = ty; i < 32; i += 8)
        tile[i][tx] = W[(long)(k0 + i) * N + n0 + tx];
    __syncthreads();
    #pragma unroll
    for (int i = ty; i < 32; i += 8)
        Wt[(long)(n0 + i) * K + k0 + tx] = (f16)tile[tx][i];
}

// V [B,S,D] fp16 -> vt [B,H,HD,S] fp16
__global__ __launch_bounds__(256) void transpose_v(
    const f16* __restrict__ V, f16* __restrict__ vt)
{
    int z = blockIdx.z, b = z >> 4, h = z & 15;
    __shared__ f16 tile[32][33];
    int s0 = blockIdx.x * 32, d0 = blockIdx.y * 32;
    int tx = threadIdx.x & 31, ty = threadIdx.x >> 5;
    #pragma unroll
    for (int i = ty; i < 32; i += 8)
        tile[i][tx] = V[((long)b * Ss + s0 + i) * Dd + h * HDd + d0 + tx];
    __syncthreads();
    #pragma unroll
    for (int i = ty; i < 32; i += 8)
        vt[(((long)b * Hh + h) * HDd + d0 + i) * Ss + s0 + tx] = tile[tx][i];
}

// embedding * sqrt(D) + sinusoidal posenc -> xh fp16
__global__ __launch_bounds__(256) void embed_pe(
    const int* __restrict__ tok, const float* __restrict__ emb,
    f16* __restrict__ xh)
{
    int bs = blockIdx.x;
    int s = bs & (Ss - 1);
    int tk = tok[bs];
    const float c = -logf(10000.f) / (float)Dd;
    for (int d = threadIdx.x; d < Dd; d += 256) {
        float div = expf((float)(d & ~1) * c);
        float ang = (float)s * div;
        float pe = (d & 1) ? cosf(ang) : sinf(ang);
        float v = emb[(long)tk * Dd + d] * 32.0f + pe;  // sqrt(1024)=32
        xh[(long)bs * Dd + d] = (f16)v;
    }
}

// x = LN(x + y) * g + b ; fp16 in/out (in-place safe: reads before writes)
__global__ __launch_bounds__(256) void add_ln(
    const f16* __restrict__ x, const f16* __restrict__ y,
    const float* __restrict__ g, const float* __restrict__ b,
    f16* __restrict__ xo)
{
    __shared__ float red[8];
    long row = blockIdx.x;
    const f16* xr = x + row * Dd;
    const f16* yr = y + row * Dd;
    float vals[4];
    float s = 0.f, s2 = 0.f;
    #pragma unroll
    for (int i = 0; i < 4; ++i) {
        int cix = threadIdx.x + i * 256;
        float v = (float)xr[cix] + (float)yr[cix];
        vals[i] = v;
        s += v; s2 += v * v;
    }
    #pragma unroll
    for (int o = 32; o > 0; o >>= 1) {
        s  += __shfl_down(s, o, 64);
        s2 += __shfl_down(s2, o, 64);
    }
    if ((threadIdx.x & 63) == 0) {
        red[threadIdx.x >> 6] = s;
        red[4 + (threadIdx.x >> 6)] = s2;
    }
    __syncthreads();
    s  = red[0] + red[1] + red[2] + red[3];
    s2 = red[4] + red[5] + red[6] + red[7];
    float mu = s * (1.f / Dd);
    float var = s2 * (1.f / Dd) - mu * mu;
    float inv = rsqrtf(var + 1e-5f);
    #pragma unroll
    for (int i = 0; i < 4; ++i) {
        int cix = threadIdx.x + i * 256;
        float o = (vals[i] - mu) * inv * g[cix] + b[cix];
        xo[row * Dd + cix] = (f16)o;
    }
}

// in-place row softmax over S=512 with mask bias; fp16. rows = 4*H*S per chunk
__global__ __launch_bounds__(256) void softmax_rows(
    f16* __restrict__ sc, const int* __restrict__ mask, int bc)
{
    __shared__ float red[4];
    long row = blockIdx.x;
    int b = bc + (int)(row >> 13);  // row / (H*S)=8192
    f16* sr = sc + row * Ss;
    int c0 = threadIdx.x, c1 = threadIdx.x + 256;
    float v0 = (float)sr[c0] + (mask[b * Ss + c0] ? 0.f : -1e9f);
    float v1 = (float)sr[c1] + (mask[b * Ss + c1] ? 0.f : -1e9f);
    float mx = fmaxf(v0, v1);
    #pragma unroll
    for (int o = 32; o > 0; o >>= 1) mx = fmaxf(mx, __shfl_down(mx, o, 64));
    if ((threadIdx.x & 63) == 0) red[threadIdx.x >> 6] = mx;
    __syncthreads();
    mx = fmaxf(fmaxf(red[0], red[1]), fmaxf(red[2], red[3]));
    __syncthreads();
    float e0 = expf(v0 - mx), e1 = expf(v1 - mx);
    float sm = e0 + e1;
    #pragma unroll
    for (int o = 32; o > 0; o >>= 1) sm += __shfl_down(sm, o, 64);
    if ((threadIdx.x & 63) == 0) red[threadIdx.x >> 6] = sm;
    __syncthreads();
    sm = red[0] + red[1] + red[2] + red[3];
    float inv = 1.f / sm;
    sr[c0] = (f16)(e0 * inv);
    sr[c1] = (f16)(e1 * inv);
}

// out[b,n] = act(pv[b,:] @ W[:,n] + bias[n]) ; K=P=64, N=D. ACT: 0 none, 1 sigmoid
template <int ACT>
__global__ __launch_bounds__(256) void pv_proj(
    const float* __restrict__ pv, const float* __restrict__ W,
    const float* __restrict__ bias, float* __restrict__ out)
{
    int n = blockIdx.x * 256 + threadIdx.x;
    int b = blockIdx.y;
    float acc = bias[n];
    #pragma unroll 8
    for (int k = 0; k < Pp; ++k)
        acc += pv[b * Pp + k] * W[(long)k * Dd + n];
    if (ACT == 1) acc = 1.f / (1.f + expf(-acc));
    out[(long)b * Dd + n] = acc;
}

// masked mean pool over S (f16 in, fp32 out)
__global__ __launch_bounds__(256) void pool_mean(
    const f16* __restrict__ x, const int* __restrict__ mask, float* __restrict__ out)
{
    int d = blockIdx.x * 256 + threadIdx.x;
    int b = blockIdx.y;
    float s = 0.f, cnt = 0.f;
    for (int ss = 0; ss < Ss; ++ss) {
        if (mask[b * Ss + ss]) { s += (float)x[((long)b * Ss + ss) * Dd + d]; cnt += 1.f; }
    }
    out[(long)b * Dd + d] = s / fmaxf(cnt, 1e-9f);
}

// small fp32 GEMM for the head: C[m,n] = act(A[m,:]@W[:,n] + bias[n] (+ add[m,n]))
// ACT: 0 none, 1 relu, 2 tanh. grid (N/256, M). K<=1024.
template <int ACT>
__global__ __launch_bounds__(256) void small_gemm(
    const float* __restrict__ A, const float* __restrict__ W,
    const float* __restrict__ bias, const float* __restrict__ add,
    float* __restrict__ C, int N, int K)
{
    __shared__ float a[1024];
    int m = blockIdx.y;
    int n = blockIdx.x * 256 + threadIdx.x;
    for (int k = threadIdx.x; k < K; k += 256) a[k] = A[(long)m * K + k];
    __syncthreads();
    float acc = bias[n];
    for (int k = 0; k < K; ++k) acc += a[k] * W[(long)k * N + n];
    if (add) acc += add[(long)m * N + n];
    if (ACT == 1) acc = fmaxf(acc, 0.f);
    if (ACT == 2) acc = tanhf(acc);
    C[(long)m * N + n] = acc;
}

extern "C" void kernel_launch(void* const* d_in, const int* in_sizes, int n_in,
                              void* d_out, int out_size, void* d_ws, size_t ws_size,
                              hipStream_t stream) {
    const int*   tok  = (const int*)d_in[0];
    const int*   mask = (const int*)d_in[1];
    const float* pv   = (const float*)d_in[2];
    const float* emb  = (const float*)d_in[3];
    const float* Wq  = (const float*)d_in[4];  const float* bq  = (const float*)d_in[5];
    const float* Wk  = (const float*)d_in[6];  const float* bk  = (const float*)d_in[7];
    const float* Wv  = (const float*)d_in[8];  const float* bvp = (const float*)d_in[9];
    const float* Wo  = (const float*)d_in[10]; const float* bo  = (const float*)d_in[11];
    const float* Wpq = (const float*)d_in[12]; const float* bpq = (const float*)d_in[13];
    const float* Wpk = (const float*)d_in[14]; const float* bpk = (const float*)d_in[15];
    const float* Wpg = (const float*)d_in[16]; const float* bpg = (const float*)d_in[17];
    const float* Wf1 = (const float*)d_in[18]; const float* bf1 = (const float*)d_in[19];
    const float* Wf2 = (const float*)d_in[20]; const float* bf2 = (const float*)d_in[21];
    const float* g1  = (const float*)d_in[22]; const float* b1  = (const float*)d_in[23];
    const float* g2  = (const float*)d_in[24]; const float* b2  = (const float*)d_in[25];
    const float* Wp1 = (const float*)d_in[26]; const float* bp1 = (const float*)d_in[27];
    const float* Wp2 = (const float*)d_in[28]; const float* bp2 = (const float*)d_in[29];
    const float* Wo1 = (const float*)d_in[30]; const float* bo1 = (const float*)d_in[31];
    const float* Wo2 = (const float*)d_in[32]; const float* bo2 = (const float*)d_in[33];
    float* outp = (float*)d_out;

    // ---- workspace carve: total ~249 MiB ----
    char* wp = (char*)d_ws;
    auto alloc = [&](size_t bytes) { char* r = wp; wp += (bytes + 255) & ~(size_t)255; return r; };
    const long DDl = (long)Dd * Dd;
    // per-layer transposed weights (fp16 [N,K])
    f16* wqT  = (f16*)alloc(DDl * 2);                      // 2 MiB
    f16* wkT  = (f16*)alloc(DDl * 2);
    f16* wvT  = (f16*)alloc(DDl * 2);
    f16* woT  = (f16*)alloc(DDl * 2);
    f16* wf1T = (f16*)alloc((size_t)DFFd * Dd * 2);        // 8 MiB
    f16* wf2T = (f16*)alloc((size_t)Dd * DFFd * 2);        // 8 MiB
    // activations (fp16)
    f16* xh   = (f16*)alloc((size_t)BS * Dd * 2);          // 32 MiB residual stream
    f16* qh   = (f16*)alloc((size_t)BS * Dd * 2);          // 32
    f16* kh   = (f16*)alloc((size_t)BS * Dd * 2);          // 32
    f16* vt   = (f16*)alloc((size_t)BS * Dd * 2);          // 32 [B,H,HD,S]
    f16* attg = (f16*)alloc((size_t)BS * Dd * 2);          // 32 gated attention out
    // region A (32 MiB): vh [BS,D] -> scores/P chunk [4,H,S,S] -> ff1 [4096,DFF]
    f16* regA = (f16*)alloc((size_t)BS * Dd * 2);
    f16* vh = regA;  f16* sc = regA;  f16* ff1 = regA;
    // tmp (32 MiB fp16): outproj / FFN2 results, consumed by add_ln
    f16* tmp  = (f16*)alloc((size_t)BS * Dd * 2);
    // small fp32 buffers
    float* pq     = (float*)alloc((size_t)Bb * Dd * 4);
    float* pk     = (float*)alloc((size_t)Bb * Dd * 4);
    float* gate   = (float*)alloc((size_t)Bb * Dd * 4);
    float* pooled = (float*)alloc((size_t)Bb * Dd * 4);
    float* h1v    = (float*)alloc((size_t)Bb * Dd * 4);
    float* comb   = (float*)alloc((size_t)Bb * Dd * 4);
    float* tvv    = (float*)alloc((size_t)Bb * Dd * 4);

    dim3 blk(256);

    // ---- embedding + posenc ----
    embed_pe<<<dim3(BS), blk, 0, stream>>>(tok, emb, xh);

    for (int l = 0; l < Ll; ++l) {
        // per-layer weight transposes (fp32 [K,N] -> fp16 [N,K])
        transpose_w<<<dim3(32, 32), blk, 0, stream>>>(Wq + l * DDl, wqT, Dd, Dd);
        transpose_w<<<dim3(32, 32), blk, 0, stream>>>(Wk + l * DDl, wkT, Dd, Dd);
        transpose_w<<<dim3(32, 32), blk, 0, stream>>>(Wv + l * DDl, wvT, Dd, Dd);
        transpose_w<<<dim3(32, 32), blk, 0, stream>>>(Wo + l * DDl, woT, Dd, Dd);
        transpose_w<<<dim3(32, 128), blk, 0, stream>>>(Wf1 + (long)l * Dd * DFFd, wf1T, Dd, DFFd);
        transpose_w<<<dim3(128, 32), blk, 0, stream>>>(Wf2 + (long)l * DFFd * Dd, wf2T, DFFd, Dd);

        // per-batch property projections
        pv_proj<0><<<dim3(4, Bb), blk, 0, stream>>>(pv, Wpq + (long)l * Pp * Dd, bpq + l * Dd, pq);
        pv_proj<0><<<dim3(4, Bb), blk, 0, stream>>>(pv, Wpk + (long)l * Pp * Dd, bpk + l * Dd, pk);
        pv_proj<1><<<dim3(4, Bb), blk, 0, stream>>>(pv, Wpg + (long)l * Pp * Dd, bpg + l * Dd, gate);

        // Q/K/V projections -> fp16 [B,S,D]
        gemm_nt<true, true, false, false><<<dim3(128, 8, 1), blk, 0, stream>>>(
            xh, wqT, qh, BS, Dd, Dd, Dd, Dd, Dd,
            0, 0, 0, 0, 0, 0, 1, bq + l * Dd, pq, 9, nullptr, 0, 0, 1.0f);
        gemm_nt<true, true, false, false><<<dim3(128, 8, 1), blk, 0, stream>>>(
            xh, wkT, kh, BS, Dd, Dd, Dd, Dd, Dd,
            0, 0, 0, 0, 0, 0, 1, bk + l * Dd, pk, 9, nullptr, 0, 0, 1.0f);
        gemm_nt<true, false, false, false><<<dim3(128, 8, 1), blk, 0, stream>>>(
            xh, wvT, vh, BS, Dd, Dd, Dd, Dd, Dd,
            0, 0, 0, 0, 0, 0, 1, bvp + l * Dd, nullptr, 0, nullptr, 0, 0, 1.0f);

        transpose_v<<<dim3(16, 2, Bb * Hh), blk, 0, stream>>>(vh, vt);
        // (vh dead from here; region A becomes the scores/P chunk)

        // attention in 4-batch chunks
        for (int bc = 0; bc < Bb; bc += 4) {
            gemm_nt<false, false, false, false><<<dim3(4, 4, 64), blk, 0, stream>>>(
                qh + (long)bc * Ss * Dd, kh + (long)bc * Ss * Dd, sc,
                Ss, Ss, HDd, Dd, Dd, Ss,
                (long)Ss * Dd, HDd, (long)Ss * Dd, HDd, (long)Hh * Ss * Ss, (long)Ss * Ss, Hh,
                nullptr, nullptr, 0, nullptr, 0, 0, 0.125f);
            softmax_rows<<<dim3(4 * Hh * Ss), blk, 0, stream>>>(sc, mask, bc);
            gemm_nt<false, false, true, false><<<dim3(4, 1, 64), blk, 0, stream>>>(
                sc, vt + (long)bc * Dd * Ss, attg + (long)bc * Ss * Dd,
                Ss, HDd, Ss, Ss, Ss, Dd,
                (long)Hh * Ss * Ss, (long)Ss * Ss, (long)Dd * Ss, (long)HDd * Ss,
                (long)Ss * Dd, HDd, Hh,
                nullptr, nullptr, 0, gate + (long)bc * Dd, Dd, HDd, 1.0f);
        }

        // output projection -> fp16 tmp, then residual+LN (in-place on xh)
        gemm_nt<true, false, false, false><<<dim3(128, 8, 1), blk, 0, stream>>>(
            attg, woT, tmp, BS, Dd, Dd, Dd, Dd, Dd,
            0, 0, 0, 0, 0, 0, 1, bo + l * Dd, nullptr, 0, nullptr, 0, 0, 1.0f);
        add_ln<<<dim3(BS), blk, 0, stream>>>(xh, tmp, g1 + l * Dd, b1 + l * Dd, xh);

        // FFN in 4 row-chunks of 4096 (ff1 = region A)
        for (int mc = 0; mc < 4; ++mc) {
            gemm_nt<true, false, false, true><<<dim3(32, 32, 1), blk, 0, stream>>>(
                xh + (long)mc * 4096 * Dd, wf1T, ff1,
                4096, DFFd, Dd, Dd, Dd, DFFd,
                0, 0, 0, 0, 0, 0, 1, bf1 + l * DFFd, nullptr, 0, nullptr, 0, 0, 1.0f);
            gemm_nt<true, false, false, false><<<dim3(32, 8, 1), blk, 0, stream>>>(
                ff1, wf2T, tmp + (long)mc * 4096 * Dd,
                4096, Dd, DFFd, DFFd, DFFd, Dd,
                0, 0, 0, 0, 0, 0, 1, bf2 + l * Dd, nullptr, 0, nullptr, 0, 0, 1.0f);
        }
        add_ln<<<dim3(BS), blk, 0, stream>>>(xh, tmp, g2 + l * Dd, b2 + l * Dd, xh);
    }

    // ---- pooling + head (fp32) ----
    pool_mean<<<dim3(4, Bb), blk, 0, stream>>>(xh, mask, pooled);
    small_gemm<1><<<dim3(4, Bb), blk, 0, stream>>>(pv, Wp1, bp1, nullptr, h1v, Dd, Pp);
    small_gemm<0><<<dim3(4, Bb), blk, 0, stream>>>(h1v, Wp2, bp2, pooled, comb, Dd, Dd);
    small_gemm<2><<<dim3(4, Bb), blk, 0, stream>>>(comb, Wo1, bo1, nullptr, tvv, Dd, Dd);
    small_gemm<0><<<dim3(4, Bb), blk, 0, stream>>>(tvv, Wo2, bo2, nullptr, outp, Dd, Dd);
}

// Round 4
// 10366.281 us; speedup vs baseline: 1.2425x; 1.2425x over previous
//
#include <hip/hip_runtime.h>
#include <math.h>
#include <stdint.h>

// Problem constants
#define Bb 32
#define Ss 512
#define Dd 1024
#define Hh 16
#define HDd 64
#define Ll 6
#define DFFd 4096
#define Pp 64
#define BS (Bb * Ss)   // 16384 token rows

typedef _Float16 f16;
typedef _Float16 f16x8 __attribute__((ext_vector_type(8)));
typedef float f32x4 __attribute__((ext_vector_type(4)));

typedef __attribute__((address_space(3))) uint8_t  lds_b;
typedef __attribute__((address_space(1))) const uint8_t gbl_b;

// ---------------------------------------------------------------------------
// NT GEMM: C[M,N] = act( scale * A[M,K] @ Bt[N,K]^T + bias + pvec ) (* mul)
// A, Bt fp16 row-major (Bt rows K-contiguous). 128x128 tile, 4 waves, each
// wave 4x4 MFMA 16x16x32 tiles. m97-style global_load_lds(16B) staging:
// row-major unpadded LDS [128][32], thread t <-> tile byte t*16 (global AND
// LDS contiguous; 4 lanes = one 64B row-chunk, coalesced). XOR chunk swizzle
// (chunk c of row r holds global chunk c ^ ((r>>1)&3)) breaks the 8-way
// ds_read_b128 bank alias of the unpadded layout; readers XOR the same way.
// OOB rows address-clamped (duplicate valid data; only feeds discarded tiles).
// ---------------------------------------------------------------------------
template <bool BIAS, bool PVEC, bool MULV, bool RELU>
__global__ __launch_bounds__(256) void gemm_nt(
    const f16* __restrict__ A, const f16* __restrict__ Bt, f16* __restrict__ C,
    int M, int N, int K, int lda, int ldb, int ldc,
    long sA1, long sA2, long sB1, long sB2, long sC1, long sC2, int nz2,
    const float* __restrict__ bias, const float* __restrict__ pvec, int pvs,
    const float* __restrict__ mul, long sM1, long sM2, float scale)
{
    __shared__ f16 As[128 * 32];   // row-major [128][32], swizzled 16B chunks
    __shared__ f16 Bs[128 * 32];

    int z = blockIdx.z;
    int z1 = z / nz2, z2 = z % nz2;
    A  += z1 * sA1 + z2 * sA2;
    Bt += z1 * sB1 + z2 * sB2;
    long coff = z1 * sC1 + z2 * sC2;
    if (MULV) mul += z1 * sM1 + z2 * sM2;

    int m0 = blockIdx.x * 128, n0 = blockIdx.y * 128;
    int t = threadIdx.x;
    int lane = t & 63, w = t >> 6;
    int wm = (w >> 1) * 64, wn = (w & 1) * 64;
    int fr = lane & 15;            // A row / B col within 16-tile
    int fs = lane >> 4;            // k-segment (8 halves each)
    int fsw = fs ^ ((fr >> 1) & 3);   // swizzled chunk for fragment reads

    // staging: thread t covers (row p*64 + t/4, chunk t%4); global chunk XORed
    int srow = t >> 2;
    int gch = (t & 3) ^ ((srow >> 1) & 3);   // (row>>1)&3 is p-invariant (64%4==0... 64/2=32, 32&3=0)
    int gmS0 = m0 + srow;       if (gmS0 >= M) gmS0 = M - 1;
    int gmS1 = m0 + 64 + srow;  if (gmS1 >= M) gmS1 = M - 1;
    int gnS0 = n0 + srow;       if (gnS0 >= N) gnS0 = N - 1;
    int gnS1 = n0 + 64 + srow;  if (gnS1 >= N) gnS1 = N - 1;
    const f16* aRow0 = A + (long)gmS0 * lda + gch * 8;
    const f16* aRow1 = A + (long)gmS1 * lda + gch * 8;
    const f16* bRow0 = Bt + (long)gnS0 * ldb + gch * 8;
    const f16* bRow1 = Bt + (long)gnS1 * ldb + gch * 8;
    // wave-uniform LDS byte bases: linear byte = p*4096 + w*1024 + lane*16
    lds_b* aDst = (lds_b*)As + w * 1024;
    lds_b* bDst = (lds_b*)Bs + w * 1024;

    f32x4 acc[4][4] = {};

    for (int k0 = 0; k0 < K; k0 += 32) {
        __syncthreads();
        __builtin_amdgcn_global_load_lds((gbl_b*)(aRow0 + k0), aDst, 16, 0, 0);
        __builtin_amdgcn_global_load_lds((gbl_b*)(aRow1 + k0), aDst + 4096, 16, 0, 0);
        __builtin_amdgcn_global_load_lds((gbl_b*)(bRow0 + k0), bDst, 16, 0, 0);
        __builtin_amdgcn_global_load_lds((gbl_b*)(bRow1 + k0), bDst + 4096, 16, 0, 0);
        __syncthreads();
        f16x8 af[4], bf[4];
        #pragma unroll
        for (int i = 0; i < 4; ++i) af[i] = *(const f16x8*)&As[(wm + i * 16 + fr) * 32 + fsw * 8];
        #pragma unroll
        for (int j = 0; j < 4; ++j) bf[j] = *(const f16x8*)&Bs[(wn + j * 16 + fr) * 32 + fsw * 8];
        #pragma unroll
        for (int i = 0; i < 4; ++i)
            #pragma unroll
            for (int j = 0; j < 4; ++j)
                acc[i][j] = __builtin_amdgcn_mfma_f32_16x16x32_f16(af[i], bf[j], acc[i][j], 0, 0, 0);
    }

    // epilogue: C/D layout col=lane&15, row=(lane>>4)*4+reg  [verified m89/m91]
    int cr = (lane >> 4) * 4;
    int cc = lane & 15;
    #pragma unroll
    for (int i = 0; i < 4; ++i) {
        #pragma unroll
        for (int j = 0; j < 4; ++j) {
            int gn = n0 + wn + j * 16 + cc;
            if (gn >= N) continue;
            float bvv = BIAS ? bias[gn] : 0.f;
            float mvv = MULV ? mul[gn] : 1.f;
            #pragma unroll
            for (int r = 0; r < 4; ++r) {
                int gm = m0 + wm + i * 16 + cr + r;
                if (gm >= M) continue;
                float v = acc[i][j][r] * scale + bvv;
                if (PVEC) v += pvec[(long)(gm >> pvs) * N + gn];
                if (MULV) v *= mvv;
                if (RELU) v = fmaxf(v, 0.f);
                C[coff + (long)gm * ldc + gn] = (f16)v;
            }
        }
    }
}

// fp32 [K,N] -> fp16 [N,K] transpose (weights), K,N multiples of 32
__global__ __launch_bounds__(256) void transpose_w(
    const float* __restrict__ W, f16* __restrict__ Wt, int K, int N)
{
    __shared__ float tile[32][33];
    int k0 = blockIdx.x * 32, n0 = blockIdx.y * 32;
    int tx = threadIdx.x & 31, ty = threadIdx.x >> 5;
    #pragma unroll
    for (int i = ty; i < 32; i += 8)
        tile[i][tx] = W[(long)(k0 + i) * N + n0 + tx];
    __syncthreads();
    #pragma unroll
    for (int i = ty; i < 32; i += 8)
        Wt[(long)(n0 + i) * K + k0 + tx] = (f16)tile[tx][i];
}

// V [B,S,D] fp16 -> vt [B,H,HD,S] fp16
__global__ __launch_bounds__(256) void transpose_v(
    const f16* __restrict__ V, f16* __restrict__ vt)
{
    int z = blockIdx.z, b = z >> 4, h = z & 15;
    __shared__ f16 tile[32][33];
    int s0 = blockIdx.x * 32, d0 = blockIdx.y * 32;
    int tx = threadIdx.x & 31, ty = threadIdx.x >> 5;
    #pragma unroll
    for (int i = ty; i < 32; i += 8)
        tile[i][tx] = V[((long)b * Ss + s0 + i) * Dd + h * HDd + d0 + tx];
    __syncthreads();
    #pragma unroll
    for (int i = ty; i < 32; i += 8)
        vt[(((long)b * Hh + h) * HDd + d0 + i) * Ss + s0 + tx] = tile[tx][i];
}

// embedding * sqrt(D) + sinusoidal posenc -> xh fp16
__global__ __launch_bounds__(256) void embed_pe(
    const int* __restrict__ tok, const float* __restrict__ emb,
    f16* __restrict__ xh)
{
    int bs = blockIdx.x;
    int s = bs & (Ss - 1);
    int tk = tok[bs];
    const float c = -logf(10000.f) / (float)Dd;
    for (int d = threadIdx.x; d < Dd; d += 256) {
        float div = expf((float)(d & ~1) * c);
        float ang = (float)s * div;
        float pe = (d & 1) ? cosf(ang) : sinf(ang);
        float v = emb[(long)tk * Dd + d] * 32.0f + pe;  // sqrt(1024)=32
        xh[(long)bs * Dd + d] = (f16)v;
    }
}

// x = LN(x + y) * g + b ; fp16 in/out (in-place safe: reads before writes)
__global__ __launch_bounds__(256) void add_ln(
    const f16* __restrict__ x, const f16* __restrict__ y,
    const float* __restrict__ g, const float* __restrict__ b,
    f16* __restrict__ xo)
{
    __shared__ float red[8];
    long row = blockIdx.x;
    const f16* xr = x + row * Dd;
    const f16* yr = y + row * Dd;
    float vals[4];
    float s = 0.f, s2 = 0.f;
    #pragma unroll
    for (int i = 0; i < 4; ++i) {
        int cix = threadIdx.x + i * 256;
        float v = (float)xr[cix] + (float)yr[cix];
        vals[i] = v;
        s += v; s2 += v * v;
    }
    #pragma unroll
    for (int o = 32; o > 0; o >>= 1) {
        s  += __shfl_down(s, o, 64);
        s2 += __shfl_down(s2, o, 64);
    }
    if ((threadIdx.x & 63) == 0) {
        red[threadIdx.x >> 6] = s;
        red[4 + (threadIdx.x >> 6)] = s2;
    }
    __syncthreads();
    s  = red[0] + red[1] + red[2] + red[3];
    s2 = red[4] + red[5] + red[6] + red[7];
    float mu = s * (1.f / Dd);
    float var = s2 * (1.f / Dd) - mu * mu;
    float inv = rsqrtf(var + 1e-5f);
    #pragma unroll
    for (int i = 0; i < 4; ++i) {
        int cix = threadIdx.x + i * 256;
        float o = (vals[i] - mu) * inv * g[cix] + b[cix];
        xo[row * Dd + cix] = (f16)o;
    }
}

// in-place row softmax over S=512 with mask bias; fp16. rows = 4*H*S per chunk
__global__ __launch_bounds__(256) void softmax_rows(
    f16* __restrict__ sc, const int* __restrict__ mask, int bc)
{
    __shared__ float red[4];
    long row = blockIdx.x;
    int b = bc + (int)(row >> 13);  // row / (H*S)=8192
    f16* sr = sc + row * Ss;
    int c0 = threadIdx.x, c1 = threadIdx.x + 256;
    float v0 = (float)sr[c0] + (mask[b * Ss + c0] ? 0.f : -1e9f);
    float v1 = (float)sr[c1] + (mask[b * Ss + c1] ? 0.f : -1e9f);
    float mx = fmaxf(v0, v1);
    #pragma unroll
    for (int o = 32; o > 0; o >>= 1) mx = fmaxf(mx, __shfl_down(mx, o, 64));
    if ((threadIdx.x & 63) == 0) red[threadIdx.x >> 6] = mx;
    __syncthreads();
    mx = fmaxf(fmaxf(red[0], red[1]), fmaxf(red[2], red[3]));
    __syncthreads();
    float e0 = expf(v0 - mx), e1 = expf(v1 - mx);
    float sm = e0 + e1;
    #pragma unroll
    for (int o = 32; o > 0; o >>= 1) sm += __shfl_down(sm, o, 64);
    if ((threadIdx.x & 63) == 0) red[threadIdx.x >> 6] = sm;
    __syncthreads();
    sm = red[0] + red[1] + red[2] + red[3];
    float inv = 1.f / sm;
    sr[c0] = (f16)(e0 * inv);
    sr[c1] = (f16)(e1 * inv);
}

// out[b,n] = act(pv[b,:] @ W[:,n] + bias[n]) ; K=P=64, N=D. ACT: 0 none, 1 sigmoid
template <int ACT>
__global__ __launch_bounds__(256) void pv_proj(
    const float* __restrict__ pv, const float* __restrict__ W,
    const float* __restrict__ bias, float* __restrict__ out)
{
    int n = blockIdx.x * 256 + threadIdx.x;
    int b = blockIdx.y;
    float acc = bias[n];
    #pragma unroll 8
    for (int k = 0; k < Pp; ++k)
        acc += pv[b * Pp + k] * W[(long)k * Dd + n];
    if (ACT == 1) acc = 1.f / (1.f + expf(-acc));
    out[(long)b * Dd + n] = acc;
}

// masked mean pool over S (f16 in, fp32 out)
__global__ __launch_bounds__(256) void pool_mean(
    const f16* __restrict__ x, const int* __restrict__ mask, float* __restrict__ out)
{
    int d = blockIdx.x * 256 + threadIdx.x;
    int b = blockIdx.y;
    float s = 0.f, cnt = 0.f;
    for (int ss = 0; ss < Ss; ++ss) {
        if (mask[b * Ss + ss]) { s += (float)x[((long)b * Ss + ss) * Dd + d]; cnt += 1.f; }
    }
    out[(long)b * Dd + d] = s / fmaxf(cnt, 1e-9f);
}

// small fp32 GEMM for the head: C[m,n] = act(A[m,:]@W[:,n] + bias[n] (+ add[m,n]))
// ACT: 0 none, 1 relu, 2 tanh. grid (N/256, M). K<=1024.
template <int ACT>
__global__ __launch_bounds__(256) void small_gemm(
    const float* __restrict__ A, const float* __restrict__ W,
    const float* __restrict__ bias, const float* __restrict__ add,
    float* __restrict__ C, int N, int K)
{
    __shared__ float a[1024];
    int m = blockIdx.y;
    int n = blockIdx.x * 256 + threadIdx.x;
    for (int k = threadIdx.x; k < K; k += 256) a[k] = A[(long)m * K + k];
    __syncthreads();
    float acc = bias[n];
    for (int k = 0; k < K; ++k) acc += a[k] * W[(long)k * N + n];
    if (add) acc += add[(long)m * N + n];
    if (ACT == 1) acc = fmaxf(acc, 0.f);
    if (ACT == 2) acc = tanhf(acc);
    C[(long)m * N + n] = acc;
}

extern "C" void kernel_launch(void* const* d_in, const int* in_sizes, int n_in,
                              void* d_out, int out_size, void* d_ws, size_t ws_size,
                              hipStream_t stream) {
    const int*   tok  = (const int*)d_in[0];
    const int*   mask = (const int*)d_in[1];
    const float* pv   = (const float*)d_in[2];
    const float* emb  = (const float*)d_in[3];
    const float* Wq  = (const float*)d_in[4];  const float* bq  = (const float*)d_in[5];
    const float* Wk  = (const float*)d_in[6];  const float* bk  = (const float*)d_in[7];
    const float* Wv  = (const float*)d_in[8];  const float* bvp = (const float*)d_in[9];
    const float* Wo  = (const float*)d_in[10]; const float* bo  = (const float*)d_in[11];
    const float* Wpq = (const float*)d_in[12]; const float* bpq = (const float*)d_in[13];
    const float* Wpk = (const float*)d_in[14]; const float* bpk = (const float*)d_in[15];
    const float* Wpg = (const float*)d_in[16]; const float* bpg = (const float*)d_in[17];
    const float* Wf1 = (const float*)d_in[18]; const float* bf1 = (const float*)d_in[19];
    const float* Wf2 = (const float*)d_in[20]; const float* bf2 = (const float*)d_in[21];
    const float* g1  = (const float*)d_in[22]; const float* b1  = (const float*)d_in[23];
    const float* g2  = (const float*)d_in[24]; const float* b2  = (const float*)d_in[25];
    const float* Wp1 = (const float*)d_in[26]; const float* bp1 = (const float*)d_in[27];
    const float* Wp2 = (const float*)d_in[28]; const float* bp2 = (const float*)d_in[29];
    const float* Wo1 = (const float*)d_in[30]; const float* bo1 = (const float*)d_in[31];
    const float* Wo2 = (const float*)d_in[32]; const float* bo2 = (const float*)d_in[33];
    float* outp = (float*)d_out;

    // ---- workspace carve: total ~249 MiB ----
    char* wp = (char*)d_ws;
    auto alloc = [&](size_t bytes) { char* r = wp; wp += (bytes + 255) & ~(size_t)255; return r; };
    const long DDl = (long)Dd * Dd;
    // per-layer transposed weights (fp16 [N,K])
    f16* wqT  = (f16*)alloc(DDl * 2);                      // 2 MiB
    f16* wkT  = (f16*)alloc(DDl * 2);
    f16* wvT  = (f16*)alloc(DDl * 2);
    f16* woT  = (f16*)alloc(DDl * 2);
    f16* wf1T = (f16*)alloc((size_t)DFFd * Dd * 2);        // 8 MiB
    f16* wf2T = (f16*)alloc((size_t)Dd * DFFd * 2);        // 8 MiB
    // activations (fp16)
    f16* xh   = (f16*)alloc((size_t)BS * Dd * 2);          // 32 MiB residual stream
    f16* qh   = (f16*)alloc((size_t)BS * Dd * 2);          // 32
    f16* kh   = (f16*)alloc((size_t)BS * Dd * 2);          // 32
    f16* vt   = (f16*)alloc((size_t)BS * Dd * 2);          // 32 [B,H,HD,S]
    f16* attg = (f16*)alloc((size_t)BS * Dd * 2);          // 32 gated attention out
    // region A (32 MiB): vh [BS,D] -> scores/P chunk [4,H,S,S] -> ff1 [4096,DFF]
    f16* regA = (f16*)alloc((size_t)BS * Dd * 2);
    f16* vh = regA;  f16* sc = regA;  f16* ff1 = regA;
    // tmp (32 MiB fp16): outproj / FFN2 results, consumed by add_ln
    f16* tmp  = (f16*)alloc((size_t)BS * Dd * 2);
    // small fp32 buffers
    float* pq     = (float*)alloc((size_t)Bb * Dd * 4);
    float* pk     = (float*)alloc((size_t)Bb * Dd * 4);
    float* gate   = (float*)alloc((size_t)Bb * Dd * 4);
    float* pooled = (float*)alloc((size_t)Bb * Dd * 4);
    float* h1v    = (float*)alloc((size_t)Bb * Dd * 4);
    float* comb   = (float*)alloc((size_t)Bb * Dd * 4);
    float* tvv    = (float*)alloc((size_t)Bb * Dd * 4);

    dim3 blk(256);

    // ---- embedding + posenc ----
    embed_pe<<<dim3(BS), blk, 0, stream>>>(tok, emb, xh);

    for (int l = 0; l < Ll; ++l) {
        // per-layer weight transposes (fp32 [K,N] -> fp16 [N,K])
        transpose_w<<<dim3(32, 32), blk, 0, stream>>>(Wq + l * DDl, wqT, Dd, Dd);
        transpose_w<<<dim3(32, 32), blk, 0, stream>>>(Wk + l * DDl, wkT, Dd, Dd);
        transpose_w<<<dim3(32, 32), blk, 0, stream>>>(Wv + l * DDl, wvT, Dd, Dd);
        transpose_w<<<dim3(32, 32), blk, 0, stream>>>(Wo + l * DDl, woT, Dd, Dd);
        transpose_w<<<dim3(32, 128), blk, 0, stream>>>(Wf1 + (long)l * Dd * DFFd, wf1T, Dd, DFFd);
        transpose_w<<<dim3(128, 32), blk, 0, stream>>>(Wf2 + (long)l * DFFd * Dd, wf2T, DFFd, Dd);

        // per-batch property projections
        pv_proj<0><<<dim3(4, Bb), blk, 0, stream>>>(pv, Wpq + (long)l * Pp * Dd, bpq + l * Dd, pq);
        pv_proj<0><<<dim3(4, Bb), blk, 0, stream>>>(pv, Wpk + (long)l * Pp * Dd, bpk + l * Dd, pk);
        pv_proj<1><<<dim3(4, Bb), blk, 0, stream>>>(pv, Wpg + (long)l * Pp * Dd, bpg + l * Dd, gate);

        // Q/K/V projections -> fp16 [B,S,D]
        gemm_nt<true, true, false, false><<<dim3(128, 8, 1), blk, 0, stream>>>(
            xh, wqT, qh, BS, Dd, Dd, Dd, Dd, Dd,
            0, 0, 0, 0, 0, 0, 1, bq + l * Dd, pq, 9, nullptr, 0, 0, 1.0f);
        gemm_nt<true, true, false, false><<<dim3(128, 8, 1), blk, 0, stream>>>(
            xh, wkT, kh, BS, Dd, Dd, Dd, Dd, Dd,
            0, 0, 0, 0, 0, 0, 1, bk + l * Dd, pk, 9, nullptr, 0, 0, 1.0f);
        gemm_nt<true, false, false, false><<<dim3(128, 8, 1), blk, 0, stream>>>(
            xh, wvT, vh, BS, Dd, Dd, Dd, Dd, Dd,
            0, 0, 0, 0, 0, 0, 1, bvp + l * Dd, nullptr, 0, nullptr, 0, 0, 1.0f);

        transpose_v<<<dim3(16, 2, Bb * Hh), blk, 0, stream>>>(vh, vt);
        // (vh dead from here; region A becomes the scores/P chunk)

        // attention in 4-batch chunks
        for (int bc = 0; bc < Bb; bc += 4) {
            gemm_nt<false, false, false, false><<<dim3(4, 4, 64), blk, 0, stream>>>(
                qh + (long)bc * Ss * Dd, kh + (long)bc * Ss * Dd, sc,
                Ss, Ss, HDd, Dd, Dd, Ss,
                (long)Ss * Dd, HDd, (long)Ss * Dd, HDd, (long)Hh * Ss * Ss, (long)Ss * Ss, Hh,
                nullptr, nullptr, 0, nullptr, 0, 0, 0.125f);
            softmax_rows<<<dim3(4 * Hh * Ss), blk, 0, stream>>>(sc, mask, bc);
            gemm_nt<false, false, true, false><<<dim3(4, 1, 64), blk, 0, stream>>>(
                sc, vt + (long)bc * Dd * Ss, attg + (long)bc * Ss * Dd,
                Ss, HDd, Ss, Ss, Ss, Dd,
                (long)Hh * Ss * Ss, (long)Ss * Ss, (long)Dd * Ss, (long)HDd * Ss,
                (long)Ss * Dd, HDd, Hh,
                nullptr, nullptr, 0, gate + (long)bc * Dd, Dd, HDd, 1.0f);
        }

        // output projection -> fp16 tmp, then residual+LN (in-place on xh)
        gemm_nt<true, false, false, false><<<dim3(128, 8, 1), blk, 0, stream>>>(
            attg, woT, tmp, BS, Dd, Dd, Dd, Dd, Dd,
            0, 0, 0, 0, 0, 0, 1, bo + l * Dd, nullptr, 0, nullptr, 0, 0, 1.0f);
        add_ln<<<dim3(BS), blk, 0, stream>>>(xh, tmp, g1 + l * Dd, b1 + l * Dd, xh);

        // FFN in 4 row-chunks of 4096 (ff1 = region A)
        for (int mc = 0; mc < 4; ++mc) {
            gemm_nt<true, false, false, true><<<dim3(32, 32, 1), blk, 0, stream>>>(
                xh + (long)mc * 4096 * Dd, wf1T, ff1,
                4096, DFFd, Dd, Dd, Dd, DFFd,
                0, 0, 0, 0, 0, 0, 1, bf1 + l * DFFd, nullptr, 0, nullptr, 0, 0, 1.0f);
            gemm_nt<true, false, false, false><<<dim3(32, 8, 1), blk, 0, stream>>>(
                ff1, wf2T, tmp + (long)mc * 4096 * Dd,
                4096, Dd, DFFd, DFFd, DFFd, Dd,
                0, 0, 0, 0, 0, 0, 1, bf2 + l * Dd, nullptr, 0, nullptr, 0, 0, 1.0f);
        }
        add_ln<<<dim3(BS), blk, 0, stream>>>(xh, tmp, g2 + l * Dd, b2 + l * Dd, xh);
    }

    // ---- pooling + head (fp32) ----
    pool_mean<<<dim3(4, Bb), blk, 0, stream>>>(xh, mask, pooled);
    small_gemm<1><<<dim3(4, Bb), blk, 0, stream>>>(pv, Wp1, bp1, nullptr, h1v, Dd, Pp);
    small_gemm<0><<<dim3(4, Bb), blk, 0, stream>>>(h1v, Wp2, bp2, pooled, comb, Dd, Dd);
    small_gemm<2><<<dim3(4, Bb), blk, 0, stream>>>(comb, Wo1, bo1, nullptr, tvv, Dd, Dd);
    small_gemm<0><<<dim3(4, Bb), blk, 0, stream>>>(tvv, Wo2, bo2, nullptr, outp, Dd, Dd);
}